// Round 1
// baseline (878.583 us; speedup 1.0000x reference)
//
#include <hip/hip_runtime.h>
#include <hip/hip_bf16.h>

// Problem constants (from reference)
#define NN 100000          // nodes
#define NE 1600000         // edges
#define NR 20              // relations
#define NRX 21             // + self-loop pseudo-relation
#define FD 32              // feature dim (in = hidden = out = 32)
#define ETOT (NE + NN)     // edges + self-loop virtual edges = 1,700,000
#define MKEYS (NRX * NN)   // sort buckets = 2,100,000
#define CHUNK 32           // edges per half-wave task
#define NCHUNK (ETOT / CHUNK)  // 53,125 (divides exactly)

static_assert(ETOT % CHUNK == 0, "chunking must be exact");

// ---------------- W basis combine: W[r] = sum_b a[r,b] V[b]; W[20] = loop ----
__global__ void k_w(const float* __restrict__ V1, const float* __restrict__ a1,
                    const float* __restrict__ lp1,
                    const float* __restrict__ V2, const float* __restrict__ a2,
                    const float* __restrict__ lp2,
                    float* __restrict__ W1, float* __restrict__ W2) {
  int t = blockIdx.x * 256 + threadIdx.x;
  if (t >= 2 * NRX * FD * FD) return;
  int l = t / (NRX * FD * FD);
  int rest = t - l * (NRX * FD * FD);
  int r = rest / (FD * FD);
  int io = rest - r * (FD * FD);
  const float* V = l ? V2 : V1;
  const float* a = l ? a2 : a1;
  const float* lp = l ? lp2 : lp1;
  float* W = l ? W2 : W1;
  float v;
  if (r == NR) {
    v = lp[io];
  } else {
    v = 0.f;
#pragma unroll
    for (int b = 0; b < 8; ++b) v += a[r * 8 + b] * V[b * FD * FD + io];
  }
  W[r * FD * FD + io] = v;
}

// ---------------- histogram over keys (rel*NN + dst) ------------------------
__global__ void k_hist(const int* __restrict__ dst, const int* __restrict__ et,
                       int* __restrict__ hist) {
  int e = blockIdx.x * 256 + threadIdx.x;
  if (e < NE) {
    atomicAdd(&hist[et[e] * NN + dst[e]], 1);
  } else if (e < ETOT) {
    atomicAdd(&hist[NR * NN + (e - NE)], 1);  // self-loop bucket (count 1)
  }
}

// ---------------- hierarchical exclusive scan (1024 elems / block) ----------
__global__ void k_scan1(int* __restrict__ data, int* __restrict__ aux, int n) {
  __shared__ int sd[256];
  int t = threadIdx.x, blk = blockIdx.x;
  int base = blk * 1024 + t * 4;
  int v[4];
#pragma unroll
  for (int j = 0; j < 4; ++j) v[j] = (base + j < n) ? data[base + j] : 0;
  int s = v[0] + v[1] + v[2] + v[3];
  sd[t] = s;
  __syncthreads();
  for (int off = 1; off < 256; off <<= 1) {
    int x = (t >= off) ? sd[t - off] : 0;
    __syncthreads();
    sd[t] += x;
    __syncthreads();
  }
  int run = sd[t] - s;  // exclusive prefix within block
  if (t == 255) aux[blk] = sd[255];
#pragma unroll
  for (int j = 0; j < 4; ++j) {
    if (base + j < n) { data[base + j] = run; run += v[j]; }
  }
}

__global__ void k_scan2(int* __restrict__ aux, int n) {  // single block, n<=2304
  __shared__ int sd[256];
  int t = threadIdx.x;
  int loc[9];
  int s = 0;
#pragma unroll
  for (int j = 0; j < 9; ++j) {
    int idx = t * 9 + j;
    int v = (idx < n) ? aux[idx] : 0;
    loc[j] = s;
    s += v;
  }
  sd[t] = s;
  __syncthreads();
  for (int off = 1; off < 256; off <<= 1) {
    int x = (t >= off) ? sd[t - off] : 0;
    __syncthreads();
    sd[t] += x;
    __syncthreads();
  }
  int excl = sd[t] - s;
#pragma unroll
  for (int j = 0; j < 9; ++j) {
    int idx = t * 9 + j;
    if (idx < n) aux[idx] = excl + loc[j];
  }
}

__global__ void k_scan3(int* __restrict__ data, const int* __restrict__ aux, int n) {
  int i = blockIdx.x * 256 + threadIdx.x;
  if (i < n) data[i] += aux[i >> 10];
}

// ---------------- scatter edges into (rel,dst)-sorted order -----------------
__global__ void k_scatter(const int* __restrict__ src, const int* __restrict__ dst,
                          const int* __restrict__ et, int* __restrict__ offs,
                          int2* __restrict__ es) {
  int e = blockIdx.x * 256 + threadIdx.x;
  if (e >= ETOT) return;
  int s, d, r;
  if (e < NE) { s = src[e]; d = dst[e]; r = et[e]; }
  else        { s = d = e - NE; r = NR; }
  int key = r * NN + d;
  int pos = atomicAdd(&offs[key], 1);
  es[pos] = make_int2((s << 5) | r, d);
}

// ---------------- init h with bias broadcast --------------------------------
__global__ void k_init(float* __restrict__ h, const float* __restrict__ b) {
  int i = blockIdx.x * 256 + threadIdx.x;
  if (i < NN * FD) h[i] = b[i & (FD - 1)];
}

__global__ void k_relu(float* __restrict__ h) {
  int i = blockIdx.x * 256 + threadIdx.x;
  if (i < NN * FD) h[i] = fmaxf(h[i], 0.f);
}

// ---------------- message pass: W in VGPRs over sorted same-rel runs --------
__global__ void __launch_bounds__(256) k_msg(const float* __restrict__ xin,
                                             const int2* __restrict__ es,
                                             const float* __restrict__ W,
                                             float* __restrict__ hout) {
  int hw = (blockIdx.x * 256 + threadIdx.x) >> 5;  // global half-wave id
  int o = threadIdx.x & 31;                        // output dim owned by lane
  int nhw = (gridDim.x * 256) >> 5;

  float Wr[32];
  for (int c = hw; c < NCHUNK; c += nhw) {
    int e0 = c * CHUNK;
    int rcur = -1;
    for (int ei = 0; ei < CHUNK; ++ei) {
      int2 md = es[e0 + ei];            // lane-uniform per half-wave (L1 hit)
      int s = md.x >> 5;
      int r = md.x & 31;
      int d = md.y;
      if (r != rcur) {                  // reload W[r] column o into registers
        rcur = r;
        const float* wp = W + r * (FD * FD) + o;
#pragma unroll
        for (int i = 0; i < 32; ++i) Wr[i] = wp[i * 32];
      }
      const float4* xp = reinterpret_cast<const float4*>(xin) + s * 8;
      float a0 = 0.f, a1 = 0.f, a2 = 0.f, a3 = 0.f;
#pragma unroll
      for (int i4 = 0; i4 < 8; i4 += 4) {
        float4 x0 = xp[i4 + 0], x1 = xp[i4 + 1], x2 = xp[i4 + 2], x3 = xp[i4 + 3];
        a0 += x0.x * Wr[(i4 + 0) * 4 + 0] + x0.y * Wr[(i4 + 0) * 4 + 1] +
              x0.z * Wr[(i4 + 0) * 4 + 2] + x0.w * Wr[(i4 + 0) * 4 + 3];
        a1 += x1.x * Wr[(i4 + 1) * 4 + 0] + x1.y * Wr[(i4 + 1) * 4 + 1] +
              x1.z * Wr[(i4 + 1) * 4 + 2] + x1.w * Wr[(i4 + 1) * 4 + 3];
        a2 += x2.x * Wr[(i4 + 2) * 4 + 0] + x2.y * Wr[(i4 + 2) * 4 + 1] +
              x2.z * Wr[(i4 + 2) * 4 + 2] + x2.w * Wr[(i4 + 2) * 4 + 3];
        a3 += x3.x * Wr[(i4 + 3) * 4 + 0] + x3.y * Wr[(i4 + 3) * 4 + 1] +
              x3.z * Wr[(i4 + 3) * 4 + 2] + x3.w * Wr[(i4 + 3) * 4 + 3];
      }
      float acc = (a0 + a1) + (a2 + a3);
      unsafeAtomicAdd(&hout[d * FD + o], acc);
    }
  }
}

// ---------------- launch ----------------------------------------------------
extern "C" void kernel_launch(void* const* d_in, const int* in_sizes, int n_in,
                              void* d_out, int out_size, void* d_ws, size_t ws_size,
                              hipStream_t stream) {
  const float* x   = (const float*)d_in[0];
  const int* src   = (const int*)d_in[1];
  const int* dst   = (const int*)d_in[2];
  const int* et    = (const int*)d_in[3];
  const float* V1  = (const float*)d_in[4];
  const float* a1  = (const float*)d_in[5];
  const float* lp1 = (const float*)d_in[6];
  const float* b1  = (const float*)d_in[7];
  const float* V2  = (const float*)d_in[8];
  const float* a2  = (const float*)d_in[9];
  const float* lp2 = (const float*)d_in[10];
  const float* b2  = (const float*)d_in[11];
  float* out = (float*)d_out;

  // workspace layout (bytes)
  char* w = (char*)d_ws;
  float* W1 = (float*)(w + 0);            //  86,016 B
  float* W2 = (float*)(w + 86016);        // ->   172,032
  int* hist = (int*)(w + 172032);         // 8,400,000 -> 8,572,032
  int* aux  = (int*)(w + 8572032);        //     8,204 -> (pad) 8,580,352
  int2* es  = (int2*)(w + 8580352);       // 13,600,000 -> 22,180,352
  float* h1 = (float*)(w + 22180352);     // 12,800,000 -> 34,980,352
  if (ws_size < 34980352) return;  // loud failure instead of corruption

  hipMemsetAsync(hist, 0, (size_t)MKEYS * 4, stream);

  k_w<<<(2 * NRX * FD * FD + 255) / 256, 256, 0, stream>>>(V1, a1, lp1, V2, a2, lp2, W1, W2);

  k_hist<<<(ETOT + 255) / 256, 256, 0, stream>>>(dst, et, hist);

  int nScanBlk = (MKEYS + 1023) / 1024;  // 2051
  k_scan1<<<nScanBlk, 256, 0, stream>>>(hist, aux, MKEYS);
  k_scan2<<<1, 256, 0, stream>>>(aux, nScanBlk);
  k_scan3<<<(MKEYS + 255) / 256, 256, 0, stream>>>(hist, aux, MKEYS);

  k_scatter<<<(ETOT + 255) / 256, 256, 0, stream>>>(src, dst, et, hist, es);

  k_init<<<(NN * FD + 255) / 256, 256, 0, stream>>>(h1, b1);
  k_init<<<(NN * FD + 255) / 256, 256, 0, stream>>>(out, b2);

  // layer 1: x -> h1
  k_msg<<<2048, 256, 0, stream>>>(x, es, W1, h1);
  k_relu<<<(NN * FD + 255) / 256, 256, 0, stream>>>(h1);
  // layer 2: relu(h1) -> out
  k_msg<<<2048, 256, 0, stream>>>(h1, es, W2, out);
}